// Round 9
// baseline (974.153 us; speedup 1.0000x reference)
//
#include <hip/hip_runtime.h>
#include <math.h>

// Sinkhorn divergence (geomloss 'sinkhorn', debias=True) with quaternion
// geodesic cost, B=8, P=2048, D=4.
//
// R9 = R8 with the batch-offset bug fixed: sink_pass_skip never applied
// "+= b*NP" to rowp, so every batch sorted/gathered batch-0 ROWS against
// batch-b columns (absmax 0.19). Skip-bound math verified consistent:
// single-acos metric, U = rad_c + (hmax+120)/c2p, W = rad_r + fmax/2,
// skip iff acos(|<cen_c,cen_r>|) > U+W (cos-space, U+W < pi/2).
// Tail passes (eps <= 0.02, 6 of 13) use the skip kernel; early/mid use
// the proven R7 kernel unchanged.

#define BATCH 8
#define NP    2048
#define NPOT  (BATCH * NP)   // 16384 floats per potential array

// acos(d) ~= sqrt(u)*(b0 + b1 u + b2 u^2 + b3 u^3), u = 1-d, |err| <= 6.7e-5
#define AC0 1.4141461f
#define AC1 0.1197803f
#define AC2 0.0180731f
#define AC3 0.0187293f

__device__ __forceinline__ float bcastf(float v) {
  return __int_as_float(__builtin_amdgcn_readfirstlane(__float_as_int(v)));
}

__device__ __forceinline__ float acos_poly(float d) {
  const float u  = fmaxf(1.0f - d, 1e-6f);
  const float sq = __builtin_amdgcn_sqrtf(u);
  return sq * fmaf(fmaf(fmaf(AC3, u, AC2), u, AC1), u, AC0);
}

// ---------------------------------------------------------------------------
// Plain pass kernel (R7, unchanged, proven)
// ---------------------------------------------------------------------------
__global__ __launch_bounds__(512, 8) void sink_pass_r7(
    const float* __restrict__ x, const float* __restrict__ y,
    const float* __restrict__ wx, const float* __restrict__ wy,
    const float* __restrict__ pot_old, float* __restrict__ pot_new,
    float eps, float c1, float seed_s,
    float B0, float B1, float B2, float B3, int use_avg)
{
  const int bid  = blockIdx.x;
  const int s    = bid >> 8;
  const int b    = (bid >> 5) & 7;
  const int rg   = bid & 31;
  const int tid  = threadIdx.x;
  const int lane = tid & 63;

  __shared__ float4 Pts[NP];
  __shared__ float  Hs[NP];

  const float4* colp; const float* colw; const float* colpot; const float4* rowp;
  if (s == 0)      { colp=(const float4*)y; colw=wy; colpot=pot_old+1*NPOT; rowp=(const float4*)x; }
  else if (s == 1) { colp=(const float4*)x; colw=wx; colpot=pot_old+0*NPOT; rowp=(const float4*)y; }
  else if (s == 2) { colp=(const float4*)x; colw=wx; colpot=pot_old+2*NPOT; rowp=(const float4*)x; }
  else             { colp=(const float4*)y; colw=wy; colpot=pot_old+3*NPOT; rowp=(const float4*)y; }
  colp += b * NP; colw += b * NP; colpot += b * NP;

  #pragma unroll
  for (int t = 0; t < 4; ++t) {
    const int idx = tid + t * 512;
    Pts[idx] = colp[idx];
    Hs[idx] = fmaf(colpot[idx], c1, __builtin_amdgcn_logf(colw[idx]));
  }
  __syncthreads();

  const int wvu = __builtin_amdgcn_readfirstlane(tid >> 6);
  const int i0  = rg * 64 + wvu * 8;
  const int oidx = s * NPOT + b * NP + i0;
  float qx[8], qy[8], qz[8], qw[8], mh[8];
  #pragma unroll
  for (int r = 0; r < 8; ++r) {
    const float4 t4 = rowp[b * NP + i0 + r];
    qx[r] = bcastf(t4.x); qy[r] = bcastf(t4.y);
    qz[r] = bcastf(t4.z); qw[r] = bcastf(t4.w);
    mh[r] = bcastf(pot_old[oidx + r] * seed_s);
  }

  float ss[8] = {0.f, 0.f, 0.f, 0.f, 0.f, 0.f, 0.f, 0.f};
  float mx[8] = {-3.0e38f, -3.0e38f, -3.0e38f, -3.0e38f,
                 -3.0e38f, -3.0e38f, -3.0e38f, -3.0e38f};

  for (int t = 0; t < 16; ++t) {
    float4 p[2]; float h[2];
    #pragma unroll
    for (int cc = 0; cc < 2; ++cc) {
      const int j = (t * 2 + cc) * 64 + lane;
      p[cc] = Pts[j];
      h[cc] = Hs[j];
    }
    #pragma unroll
    for (int r = 0; r < 8; ++r) {
      #pragma unroll
      for (int cc = 0; cc < 2; ++cc) {
        const float dt = fmaf(qx[r], p[cc].x,
                          fmaf(qy[r], p[cc].y,
                           fmaf(qz[r], p[cc].z, qw[r] * p[cc].w)));
        const float u  = fmaxf(1.0f - fabsf(dt), 1e-6f);
        const float sq = __builtin_amdgcn_sqrtf(u);
        const float pl = fmaf(fmaf(fmaf(B3, u, B2), u, B1), u, B0);
        const float v  = fmaf(sq, -pl, h[cc]);
        mx[r] = fmaxf(mx[r], v);
        ss[r] += __builtin_amdgcn_exp2f(v - mh[r]);
      }
    }
  }

  #pragma unroll
  for (int r = 0; r < 8; ++r) {
    float sv = ss[r], mv = mx[r];
    #pragma unroll
    for (int off = 32; off >= 1; off >>= 1) {
      sv += __shfl_xor(sv, off, 64);
      mv = fmaxf(mv, __shfl_xor(mv, off, 64));
    }
    ss[r] = sv; mx[r] = mv;
  }

  #pragma unroll
  for (int r = 0; r < 8; ++r) {
    const bool good = (ss[r] >= 8.6736174e-19f) && (ss[r] <= 1.1529215e18f);
    if (!good) {
      mh[r] = mx[r];
      float sv = 0.0f;
      for (int t = 0; t < 32; ++t) {
        const int j = t * 64 + lane;
        const float4 p = Pts[j];
        const float dt = fmaf(qx[r], p.x,
                          fmaf(qy[r], p.y,
                           fmaf(qz[r], p.z, qw[r] * p.w)));
        const float u  = fmaxf(1.0f - fabsf(dt), 1e-6f);
        const float sq = __builtin_amdgcn_sqrtf(u);
        const float pl = fmaf(fmaf(fmaf(B3, u, B2), u, B1), u, B0);
        const float v  = fmaf(sq, -pl, Hs[j]);
        sv += __builtin_amdgcn_exp2f(v - mh[r]);
      }
      #pragma unroll
      for (int off = 32; off >= 1; off >>= 1)
        sv += __shfl_xor(sv, off, 64);
      ss[r] = sv;
    }
  }

  if (lane == 0) {
    #pragma unroll
    for (int r = 0; r < 8; ++r) {
      float res = -eps * 0.69314718055994531f
                * (mh[r] + __builtin_amdgcn_logf(ss[r]));
      if (use_avg) res = 0.5f * (pot_old[oidx + r] + res);
      pot_new[oidx + r] = res;
    }
  }
}

// ---------------------------------------------------------------------------
// Skip pass kernel (tail eps): in-LDS clustering + conservative chunk skip
// ---------------------------------------------------------------------------

__device__ __forceinline__ int quat_key(float4 q) {
  // canonicalize sign (comp0 >= 0), Morton-interleave 3x3-bit grid on c1,c2,c3
  if (q.x < 0.0f) { q.y = -q.y; q.z = -q.z; q.w = -q.w; }
  int g1 = min(7, max(0, (int)((q.y + 1.0f) * 4.0f)));
  int g2 = min(7, max(0, (int)((q.z + 1.0f) * 4.0f)));
  int g3 = min(7, max(0, (int)((q.w + 1.0f) * 4.0f)));
  int k = 0;
  #pragma unroll
  for (int b = 0; b < 3; ++b) {
    k |= ((g1 >> b) & 1) << (3 * b + 2);
    k |= ((g2 >> b) & 1) << (3 * b + 1);
    k |= ((g3 >> b) & 1) << (3 * b + 0);
  }
  return k;   // 9 bits, < 512
}

__device__ void sort2048(const float4* __restrict__ arr,
                         unsigned short* perm, unsigned short* keys,
                         unsigned int* hist, int tid, int lane)
{
  __syncthreads();                       // prior users of scratch done
  if (tid < 512) hist[tid] = 0;
  __syncthreads();
  for (int t = tid; t < NP; t += 512) {
    const int k = quat_key(arr[t]);
    keys[t] = (unsigned short)k;
    atomicAdd(&hist[k], 1u);
  }
  __syncthreads();
  if (tid < 64) {                        // exclusive scan of 512 bins (wave 0)
    const int base = tid * 8;
    unsigned int v[8], s = 0;
    #pragma unroll
    for (int k = 0; k < 8; ++k) { v[k] = hist[base + k]; s += v[k]; }
    unsigned int incl = s;
    #pragma unroll
    for (int off = 1; off < 64; off <<= 1) {
      unsigned int n = __shfl_up(incl, off, 64);
      if (lane >= off) incl += n;
    }
    unsigned int run = incl - s;         // exclusive prefix of this lane's 8
    #pragma unroll
    for (int k = 0; k < 8; ++k) { hist[base + k] = run; run += v[k]; }
  }
  __syncthreads();
  for (int t = tid; t < NP; t += 512) {
    const unsigned int pos = atomicAdd(&hist[(int)keys[t]], 1u);
    perm[pos] = (unsigned short)t;
  }
  __syncthreads();
}

#define SKIP_BAND 120.0f

__global__ __launch_bounds__(512, 6) void sink_pass_skip(
    const float* __restrict__ x, const float* __restrict__ y,
    const float* __restrict__ wx, const float* __restrict__ wy,
    const float* __restrict__ pot_old, float* __restrict__ pot_new,
    float eps, float c1, float seed_s, float c2p /* 2*log2e/eps */,
    float B0, float B1, float B2, float B3, int use_avg)
{
  const int bid  = blockIdx.x;           // grid 1024: s(4) x b(8) x rg(32)
  const int s    = bid >> 8;
  const int b    = (bid >> 5) & 7;
  const int rg   = bid & 31;
  const int tid  = threadIdx.x;
  const int lane = tid & 63;

  __shared__ float4 Pts[NP];             // 32768 (sorted, sign-flipped)
  __shared__ float  Hs[NP];              //  8192 (sorted)
  __shared__ float4 Cent[32];            //   512 chunk centroids
  __shared__ float4 Ucs[32];             //   512 (U, cosU, sinU, -)
  __shared__ unsigned short PermA[NP];   //  4096 col perm / later key scratch
  __shared__ unsigned short PermB[NP];   //  4096 key scratch / later row perm
  __shared__ unsigned int Hist[512];     //  2048

  const float4* colp; const float* colw; const float* colpot; const float4* rowp;
  if (s == 0)      { colp=(const float4*)y; colw=wy; colpot=pot_old+1*NPOT; rowp=(const float4*)x; }
  else if (s == 1) { colp=(const float4*)x; colw=wx; colpot=pot_old+0*NPOT; rowp=(const float4*)y; }
  else if (s == 2) { colp=(const float4*)x; colw=wx; colpot=pot_old+2*NPOT; rowp=(const float4*)x; }
  else             { colp=(const float4*)y; colw=wy; colpot=pot_old+3*NPOT; rowp=(const float4*)y; }
  colp += b * NP; colw += b * NP; colpot += b * NP;
  rowp += b * NP;            // <<< R9 FIX: was missing, rows came from batch 0

  // ---- sort columns, gather-stage Pts/Hs in sorted order
  sort2048(colp, PermA, PermB, Hist, tid, lane);
  for (int t = tid; t < NP; t += 512) {
    const int j = PermA[t];
    float4 q = colp[j];
    if (q.x < 0.0f) { q.x = -q.x; q.y = -q.y; q.z = -q.z; q.w = -q.w; }
    Pts[t] = q;
    Hs[t] = fmaf(colpot[j], c1, __builtin_amdgcn_logf(colw[j]));
  }
  __syncthreads();

  // ---- chunk meta: centroid, radius, h_max per 64-col chunk (16 thr/chunk)
  {
    const int ch = tid >> 4, sub = tid & 15;
    float sx = 0, sy = 0, sz = 0, sw = 0;
    #pragma unroll
    for (int k = 0; k < 4; ++k) {
      const float4 p = Pts[ch * 64 + sub * 4 + k];
      sx += p.x; sy += p.y; sz += p.z; sw += p.w;
    }
    #pragma unroll
    for (int off = 1; off < 16; off <<= 1) {
      sx += __shfl_xor(sx, off, 16); sy += __shfl_xor(sy, off, 16);
      sz += __shfl_xor(sz, off, 16); sw += __shfl_xor(sw, off, 16);
    }
    const float n2 = sx * sx + sy * sy + sz * sz + sw * sw;
    const bool degen = (n2 < 1024.0f);   // |mean| < 0.5
    const float inv = rsqrtf(fmaxf(n2, 1e-12f));
    const float cx = sx * inv, cy = sy * inv, cz = sz * inv, cw = sw * inv;
    float rmax = 0.0f, hmax = -3.0e38f;
    #pragma unroll
    for (int k = 0; k < 4; ++k) {
      const int idx = ch * 64 + sub * 4 + k;
      const float4 p = Pts[idx];
      const float d = fminf(fabsf(p.x * cx + p.y * cy + p.z * cz + p.w * cw), 1.0f);
      rmax = fmaxf(rmax, acos_poly(d));
      hmax = fmaxf(hmax, Hs[idx]);
    }
    #pragma unroll
    for (int off = 1; off < 16; off <<= 1) {
      rmax = fmaxf(rmax, __shfl_xor(rmax, off, 16));
      hmax = fmaxf(hmax, __shfl_xor(hmax, off, 16));
    }
    if (sub == 0) {
      const float rad = degen ? 10.0f : (rmax + 0.01f);
      const float U = rad + (hmax + SKIP_BAND) / c2p;
      Cent[ch] = make_float4(cx, cy, cz, cw);
      Ucs[ch]  = make_float4(U, cosf(U), sinf(U), 0.0f);
    }
  }

  // ---- sort rows (PermB becomes row perm; PermA reused as key scratch)
  sort2048(rowp, PermB, PermA, Hist, tid, lane);

  // ---- this wave's 8 rows (sorted-adjacent) -> SGPRs
  const int wvu = __builtin_amdgcn_readfirstlane(tid >> 6);
  const int obase = s * NPOT + b * NP;
  int orig[8];
  float qx[8], qy[8], qz[8], qw[8], mh[8];
  float bx = 0, by = 0, bz = 0, bw = 0, fmaxp = -3.0e38f;
  #pragma unroll
  for (int r = 0; r < 8; ++r) {
    const int o = (int)PermB[rg * 64 + wvu * 8 + r];
    orig[r] = o;
    float4 t4 = rowp[o];
    if (t4.x < 0.0f) { t4.x = -t4.x; t4.y = -t4.y; t4.z = -t4.z; t4.w = -t4.w; }
    qx[r] = bcastf(t4.x); qy[r] = bcastf(t4.y);
    qz[r] = bcastf(t4.z); qw[r] = bcastf(t4.w);
    const float fp = bcastf(pot_old[obase + o]);
    mh[r] = fp * seed_s;
    fmaxp = fmaxf(fmaxp, fp);
    bx += qx[r]; by += qy[r]; bz += qz[r]; bw += qw[r];
  }
  const float bn2 = bx * bx + by * by + bz * bz + bw * bw;
  float rrad;
  const float binv = rsqrtf(fmaxf(bn2, 1e-12f));
  bx *= binv; by *= binv; bz *= binv; bw *= binv;
  if (bn2 < 16.0f) rrad = 10.0f;       // |mean| < 0.5: never skip
  else {
    rrad = 0.0f;
    #pragma unroll
    for (int r = 0; r < 8; ++r) {
      const float d = fminf(fabsf(qx[r] * bx + qy[r] * by + qz[r] * bz + qw[r] * bw), 1.0f);
      rrad = fmaxf(rrad, acos_poly(d));
    }
    rrad += 0.01f;
  }
  const float W = rrad + 0.5f * fmaxp; // theta-units: C = 2*theta
  const float cosW = cosf(W), sinW = sinf(W);

  float ss[8] = {0.f, 0.f, 0.f, 0.f, 0.f, 0.f, 0.f, 0.f};

  for (int ch = 0; ch < 32; ++ch) {
    const float4 cen = Cent[ch];
    const float4 ucs = Ucs[ch];
    const float dc = fabsf(bx * cen.x + by * cen.y + bz * cen.z + bw * cen.w);
    const float D = fmaf(ucs.y, cosW, -(ucs.z * sinW));   // cos(U+W)
    if ((ucs.x + W < 1.5707f) && (dc < D)) continue;      // provably < 2^-120
    const int j = ch * 64 + lane;
    const float4 p = Pts[j];
    const float h = Hs[j];
    #pragma unroll
    for (int r = 0; r < 8; ++r) {
      const float dt = fmaf(qx[r], p.x,
                        fmaf(qy[r], p.y, fmaf(qz[r], p.z, qw[r] * p.w)));
      const float u  = fmaxf(1.0f - fabsf(dt), 1e-6f);
      const float sq = __builtin_amdgcn_sqrtf(u);
      const float pl = fmaf(fmaf(fmaf(B3, u, B2), u, B1), u, B0);
      const float v  = fmaf(sq, -pl, h);
      ss[r] += __builtin_amdgcn_exp2f(v - mh[r]);
    }
  }

  #pragma unroll
  for (int r = 0; r < 8; ++r) {
    float sv = ss[r];
    #pragma unroll
    for (int off = 32; off >= 1; off >>= 1)
      sv += __shfl_xor(sv, off, 64);
    ss[r] = sv;
  }

  // safety net: band check -> exact two-phase full re-sweep (no skipping)
  #pragma unroll
  for (int r = 0; r < 8; ++r) {
    const bool good = (ss[r] >= 8.6736174e-19f) && (ss[r] <= 1.1529215e18f);
    if (!good) {
      float mv = -3.0e38f;
      for (int t = 0; t < 32; ++t) {
        const int j = t * 64 + lane;
        const float4 p = Pts[j];
        const float dt = fmaf(qx[r], p.x,
                          fmaf(qy[r], p.y, fmaf(qz[r], p.z, qw[r] * p.w)));
        const float u  = fmaxf(1.0f - fabsf(dt), 1e-6f);
        const float sq = __builtin_amdgcn_sqrtf(u);
        const float pl = fmaf(fmaf(fmaf(B3, u, B2), u, B1), u, B0);
        mv = fmaxf(mv, fmaf(sq, -pl, Hs[j]));
      }
      #pragma unroll
      for (int off = 32; off >= 1; off >>= 1)
        mv = fmaxf(mv, __shfl_xor(mv, off, 64));
      mh[r] = mv;
      float sv = 0.0f;
      for (int t = 0; t < 32; ++t) {
        const int j = t * 64 + lane;
        const float4 p = Pts[j];
        const float dt = fmaf(qx[r], p.x,
                          fmaf(qy[r], p.y, fmaf(qz[r], p.z, qw[r] * p.w)));
        const float u  = fmaxf(1.0f - fabsf(dt), 1e-6f);
        const float sq = __builtin_amdgcn_sqrtf(u);
        const float pl = fmaf(fmaf(fmaf(B3, u, B2), u, B1), u, B0);
        sv += __builtin_amdgcn_exp2f(fmaf(sq, -pl, Hs[j]) - mh[r]);
      }
      #pragma unroll
      for (int off = 32; off >= 1; off >>= 1)
        sv += __shfl_xor(sv, off, 64);
      ss[r] = sv;
    }
  }

  if (lane == 0) {
    #pragma unroll
    for (int r = 0; r < 8; ++r) {
      float res = -eps * 0.69314718055994531f
                * (mh[r] + __builtin_amdgcn_logf(ss[r]));
      const int oi = obase + orig[r];
      if (use_avg) res = 0.5f * (pot_old[oi] + res);
      pot_new[oi] = res;
    }
  }
}

// ---------------------------------------------------------------------------

__global__ __launch_bounds__(256) void loss_kernel(
    const float* __restrict__ pot, const float* __restrict__ wx,
    const float* __restrict__ wy, float* __restrict__ out)
{
  const int tid = threadIdx.x;
  double acc = 0.0;
  for (int idx = tid; idx < NPOT; idx += 256) {
    acc += (double)wx[idx] * ((double)pot[0 * NPOT + idx] - (double)pot[2 * NPOT + idx]);
    acc += (double)wy[idx] * ((double)pot[1 * NPOT + idx] - (double)pot[3 * NPOT + idx]);
  }
  #pragma unroll
  for (int off = 32; off >= 1; off >>= 1)
    acc += __shfl_xor(acc, off, 64);
  __shared__ double wsum[4];
  if ((tid & 63) == 0) wsum[tid >> 6] = acc;
  __syncthreads();
  if (tid == 0)
    out[0] = (float)((wsum[0] + wsum[1] + wsum[2] + wsum[3]) / (double)BATCH);
}

extern "C" void kernel_launch(void* const* d_in, const int* in_sizes, int n_in,
                              void* d_out, int out_size, void* d_ws, size_t ws_size,
                              hipStream_t stream)
{
  const float* x  = (const float*)d_in[0];
  const float* y  = (const float*)d_in[1];
  const float* wx = (const float*)d_in[2];
  const float* wy = (const float*)d_in[3];

  float* pot[2];
  pot[0] = (float*)d_ws;
  pot[1] = pot[0] + 4 * NPOT;     // 512 KB total, proven safe

  double eps_list[16]; int ne = 0;
  eps_list[ne++] = 3.15 * 3.15;
  const double stop = 2.0 * log(0.01), step = 2.0 * log(0.5);
  for (double e = 2.0 * log(3.15); e > stop; e += step) eps_list[ne++] = exp(e);
  eps_list[ne++] = 0.01 * 0.01;   // ne == 11

  const double LOG2E = 1.4426950408889634;
  const double b0 = 1.4141461, b1 = 0.1197803, b2 = 0.0180731, b3 = 0.0187293;
  const dim3 grid(1024), blkPass(512), blkLoss(256);
  int cur = 0;

  auto launch_pass = [&](double e, float c1f, float seedf, int avg) {
    const double sc = 2.0 * LOG2E / e;
    if (e <= 0.02) {   // tail regime: sparsity pays
      hipLaunchKernelGGL(sink_pass_skip, grid, blkPass, 0, stream,
          x, y, wx, wy, pot[cur], pot[1 - cur],
          (float)e, c1f, seedf, (float)sc,
          (float)(b0 * sc), (float)(b1 * sc), (float)(b2 * sc), (float)(b3 * sc), avg);
    } else {
      hipLaunchKernelGGL(sink_pass_r7, grid, blkPass, 0, stream,
          x, y, wx, wy, pot[cur], pot[1 - cur],
          (float)e, c1f, seedf,
          (float)(b0 * sc), (float)(b1 * sc), (float)(b2 * sc), (float)(b3 * sc), avg);
    }
    cur ^= 1;
  };

  // init pass: no potential in h, m_hat = 0, replace-mode
  launch_pass(eps_list[0], 0.0f, 0.0f, 0);
  // annealing loop, averaging update
  for (int k = 0; k < ne; ++k) {
    const double e = eps_list[k];
    launch_pass(e, (float)(LOG2E / e), (float)(-LOG2E / e), 1);
  }
  // final extrapolation, replace-mode
  {
    const double e = eps_list[ne - 1];
    launch_pass(e, (float)(LOG2E / e), (float)(-LOG2E / e), 0);
  }

  hipLaunchKernelGGL(loss_kernel, dim3(1), blkLoss, 0, stream,
      pot[cur], wx, wy, (float*)d_out);
}

// Round 10
// 794.243 us; speedup vs baseline: 1.2265x; 1.2265x over previous
//
#include <hip/hip_runtime.h>
#include <math.h>

// Sinkhorn divergence (geomloss 'sinkhorn', debias=True) with quaternion
// geodesic cost, B=8, P=2048, D=4.
//
// R10 = consolidation. R9's tail-pass skip kernel regressed (97us vs 67us:
// ~zero chunks skipped due to a sign error in the skip bound [+f/2 instead
// of -f/2] and loose Morton chunk radii, plus 2.8M LDS bank conflicts from
// the in-LDS sorts). Reverted: ALL 13 passes use the proven R7 structure.
// One validated trim: the online max (mx) is dropped from the main loop
// (1 VALU/elem); the band-check safety net now does a two-phase re-sweep
// (phase 1: exact row max, phase 2: sum) -- same pattern as R9's net.
// Main loop per element: 12 VALU + 2 trans (sqrt, exp2).
// Block 512 thr (8 waves), 40KB LDS -> 4 blocks/CU = 32 waves/CU; 8 rows
// per wave in SGPRs; seeded log2-domain softmin (m_hat from f_prev);
// butterfly add-reduce; acos deg-3 poly in u = 1-d (err 6.7e-5).

#define BATCH 8
#define NP    2048
#define NPOT  (BATCH * NP)   // 16384 floats per potential array

__device__ __forceinline__ float bcastf(float v) {
  return __int_as_float(__builtin_amdgcn_readfirstlane(__float_as_int(v)));
}

__global__ __launch_bounds__(512, 8) void sink_pass_r10(
    const float* __restrict__ x, const float* __restrict__ y,
    const float* __restrict__ wx, const float* __restrict__ wy,
    const float* __restrict__ pot_old, float* __restrict__ pot_new,
    float eps, float c1 /* log2e/eps, 0 on init */,
    float seed_s /* -log2e/eps, 0 on init */,
    float B0, float B1, float B2, float B3 /* acos(u)-poly * 2*log2e/eps */,
    int use_avg)
{
  // grid = 1024 blocks: s (4) x b (8) x rowgroup (32 of 64 rows each).
  const int bid  = blockIdx.x;
  const int s    = bid >> 8;           // 0=f_ba 1=g_ab 2=f_aa 3=g_bb
  const int b    = (bid >> 5) & 7;
  const int rg   = bid & 31;
  const int tid  = threadIdx.x;
  const int lane = tid & 63;

  __shared__ float4 Pts[NP];   // 32 KB
  __shared__ float  Hs[NP];    //  8 KB

  // Stream selection (block-uniform):
  const float4* colp; const float* colw; const float* colpot; const float4* rowp;
  if (s == 0)      { colp=(const float4*)y; colw=wy; colpot=pot_old+1*NPOT; rowp=(const float4*)x; }
  else if (s == 1) { colp=(const float4*)x; colw=wx; colpot=pot_old+0*NPOT; rowp=(const float4*)y; }
  else if (s == 2) { colp=(const float4*)x; colw=wx; colpot=pot_old+2*NPOT; rowp=(const float4*)x; }
  else             { colp=(const float4*)y; colw=wy; colpot=pot_old+3*NPOT; rowp=(const float4*)y; }
  colp += b * NP; colw += b * NP; colpot += b * NP;

  #pragma unroll
  for (int t = 0; t < 4; ++t) {
    const int idx = tid + t * 512;
    Pts[idx] = colp[idx];
    // h_j in log2 domain. c1==0 on init: poison*0 == 0.
    Hs[idx] = fmaf(colpot[idx], c1, __builtin_amdgcn_logf(colw[idx]));
  }
  __syncthreads();

  // This wave's 8 rows; quaternions and m_hat seeds broadcast into SGPRs.
  const int wvu = __builtin_amdgcn_readfirstlane(tid >> 6);
  const int i0  = rg * 64 + wvu * 8;
  const int oidx = s * NPOT + b * NP + i0;
  float qx[8], qy[8], qz[8], qw[8], mh[8];
  #pragma unroll
  for (int r = 0; r < 8; ++r) {
    const float4 t4 = rowp[b * NP + i0 + r];
    qx[r] = bcastf(t4.x); qy[r] = bcastf(t4.y);
    qz[r] = bcastf(t4.z); qw[r] = bcastf(t4.w);
    // m_hat = -f_prev*log2e/eps (log2-domain estimate of the row lse).
    mh[r] = bcastf(pot_old[oidx + r] * seed_s);
  }

  float ss[8] = {0.f, 0.f, 0.f, 0.f, 0.f, 0.f, 0.f, 0.f};

  for (int t = 0; t < 16; ++t) {       // 16 x 2 cols x 64 lanes = 2048 cols
    float4 p[2]; float h[2];
    #pragma unroll
    for (int cc = 0; cc < 2; ++cc) {
      const int j = (t * 2 + cc) * 64 + lane;
      p[cc] = Pts[j];
      h[cc] = Hs[j];
    }
    #pragma unroll
    for (int r = 0; r < 8; ++r) {
      #pragma unroll
      for (int cc = 0; cc < 2; ++cc) {
        const float dt = fmaf(qx[r], p[cc].x,
                          fmaf(qy[r], p[cc].y,
                           fmaf(qz[r], p[cc].z, qw[r] * p[cc].w)));
        const float u  = fmaxf(1.0f - fabsf(dt), 1e-6f);
        const float sq = __builtin_amdgcn_sqrtf(u);
        const float pl = fmaf(fmaf(fmaf(B3, u, B2), u, B1), u, B0);
        const float v  = fmaf(sq, -pl, h[cc]);   // h - (C/eps)*log2e
        ss[r] += __builtin_amdgcn_exp2f(v - mh[r]);
      }
    }
  }

  // Butterfly add-reduce; results bit-identical across lanes.
  #pragma unroll
  for (int r = 0; r < 8; ++r) {
    float sv = ss[r];
    #pragma unroll
    for (int off = 32; off >= 1; off >>= 1)
      sv += __shfl_xor(sv, off, 64);
    ss[r] = sv;
  }

  // Safety net: rows whose seeded sum left the safe band get a two-phase
  // exact re-sweep (phase 1: true max, phase 2: sum). Wave-uniform branch;
  // catches underflow, overflow, inf, NaN.
  #pragma unroll
  for (int r = 0; r < 8; ++r) {
    const bool good = (ss[r] >= 8.6736174e-19f) && (ss[r] <= 1.1529215e18f);
    if (!good) {
      float mv = -3.0e38f;
      for (int t = 0; t < 32; ++t) {
        const int j = t * 64 + lane;
        const float4 p = Pts[j];
        const float dt = fmaf(qx[r], p.x,
                          fmaf(qy[r], p.y, fmaf(qz[r], p.z, qw[r] * p.w)));
        const float u  = fmaxf(1.0f - fabsf(dt), 1e-6f);
        const float sq = __builtin_amdgcn_sqrtf(u);
        const float pl = fmaf(fmaf(fmaf(B3, u, B2), u, B1), u, B0);
        mv = fmaxf(mv, fmaf(sq, -pl, Hs[j]));
      }
      #pragma unroll
      for (int off = 32; off >= 1; off >>= 1)
        mv = fmaxf(mv, __shfl_xor(mv, off, 64));
      mh[r] = mv;
      float sv = 0.0f;
      for (int t = 0; t < 32; ++t) {
        const int j = t * 64 + lane;
        const float4 p = Pts[j];
        const float dt = fmaf(qx[r], p.x,
                          fmaf(qy[r], p.y, fmaf(qz[r], p.z, qw[r] * p.w)));
        const float u  = fmaxf(1.0f - fabsf(dt), 1e-6f);
        const float sq = __builtin_amdgcn_sqrtf(u);
        const float pl = fmaf(fmaf(fmaf(B3, u, B2), u, B1), u, B0);
        sv += __builtin_amdgcn_exp2f(fmaf(sq, -pl, Hs[j]) - mh[r]);
      }
      #pragma unroll
      for (int off = 32; off >= 1; off >>= 1)
        sv += __shfl_xor(sv, off, 64);
      ss[r] = sv;
    }
  }

  if (lane == 0) {
    #pragma unroll
    for (int r = 0; r < 8; ++r) {
      // softmin = -eps * ln2 * (m_hat + log2(sum))
      float res = -eps * 0.69314718055994531f
                * (mh[r] + __builtin_amdgcn_logf(ss[r]));
      if (use_avg) res = 0.5f * (pot_old[oidx + r] + res);
      pot_new[oidx + r] = res;
    }
  }
}

__global__ __launch_bounds__(256) void loss_kernel(
    const float* __restrict__ pot, const float* __restrict__ wx,
    const float* __restrict__ wy, float* __restrict__ out)
{
  const int tid = threadIdx.x;
  double acc = 0.0;
  for (int idx = tid; idx < NPOT; idx += 256) {
    acc += (double)wx[idx] * ((double)pot[0 * NPOT + idx] - (double)pot[2 * NPOT + idx]);
    acc += (double)wy[idx] * ((double)pot[1 * NPOT + idx] - (double)pot[3 * NPOT + idx]);
  }
  #pragma unroll
  for (int off = 32; off >= 1; off >>= 1)
    acc += __shfl_xor(acc, off, 64);
  __shared__ double wsum[4];
  if ((tid & 63) == 0) wsum[tid >> 6] = acc;
  __syncthreads();
  if (tid == 0)
    out[0] = (float)((wsum[0] + wsum[1] + wsum[2] + wsum[3]) / (double)BATCH);
}

extern "C" void kernel_launch(void* const* d_in, const int* in_sizes, int n_in,
                              void* d_out, int out_size, void* d_ws, size_t ws_size,
                              hipStream_t stream)
{
  const float* x  = (const float*)d_in[0];
  const float* y  = (const float*)d_in[1];
  const float* wx = (const float*)d_in[2];
  const float* wy = (const float*)d_in[3];

  float* pot[2];
  pot[0] = (float*)d_ws;
  pot[1] = pot[0] + 4 * NPOT;     // 512 KB total, proven safe

  // geomloss epsilon_schedule(p=2, diameter=3.15, blur=0.01, scaling=0.5)
  double eps_list[16]; int ne = 0;
  eps_list[ne++] = 3.15 * 3.15;
  const double stop = 2.0 * log(0.01), step = 2.0 * log(0.5);
  for (double e = 2.0 * log(3.15); e > stop; e += step) eps_list[ne++] = exp(e);
  eps_list[ne++] = 0.01 * 0.01;   // ne == 11

  const double LOG2E = 1.4426950408889634;
  // acos(d) ~= sqrt(u)*(b0 + b1 u + b2 u^2 + b3 u^3), u = 1-d, |err|<=6.7e-5
  const double b0 = 1.4141461, b1 = 0.1197803, b2 = 0.0180731, b3 = 0.0187293;
  const dim3 grid(1024), blkPass(512), blkLoss(256);
  int cur = 0;

  auto launch_pass = [&](double e, float c1f, float seedf, int avg) {
    const double sc = 2.0 * LOG2E / e;
    hipLaunchKernelGGL(sink_pass_r10, grid, blkPass, 0, stream,
        x, y, wx, wy, pot[cur], pot[1 - cur],
        (float)e, c1f, seedf,
        (float)(b0 * sc), (float)(b1 * sc), (float)(b2 * sc), (float)(b3 * sc), avg);
    cur ^= 1;
  };

  // init pass: no potential in h, m_hat = 0, replace-mode
  launch_pass(eps_list[0], 0.0f, 0.0f, 0);
  // annealing loop, averaging update
  for (int k = 0; k < ne; ++k) {
    const double e = eps_list[k];
    launch_pass(e, (float)(LOG2E / e), (float)(-LOG2E / e), 1);
  }
  // final extrapolation, replace-mode
  {
    const double e = eps_list[ne - 1];
    launch_pass(e, (float)(LOG2E / e), (float)(-LOG2E / e), 0);
  }

  hipLaunchKernelGGL(loss_kernel, dim3(1), blkLoss, 0, stream,
      pot[cur], wx, wy, (float*)d_out);
}

// Round 11
// 597.885 us; speedup vs baseline: 1.6293x; 1.3284x over previous
//
#include <hip/hip_runtime.h>
#include <math.h>

// Sinkhorn divergence (geomloss 'sinkhorn', debias=True) with quaternion
// geodesic cost, B=8, P=2048, D=4.
//
// R11 = R10 + u16 cost-matrix cache. R2's fallback proved ws < 268.96 MB --
// suspiciously 524KB over 256 MiB, so ws is likely exactly 256 MiB. Three
// u16 matrices (Cxy, Cyx, Cxx; 192 MiB) + pot ping-pong (512 KB) fit; C_yy
// is recomputed (R10 body). Decode costs 5 VALU + 1 trans/elem (~27 cyc) vs
// recompute 12 VALU + 2 trans (~56 cyc) -- trans (16 cyc blocking, measured
// R10 fit) is 57% of the budget, and decode halves it. u16 quantization:
// C err <= pi/131070 = 2.4e-5 -> softmin err same order (eps cancels),
// negligible vs 4.35e-3 threshold. Mats are pass-invariant and L3-resident
// (192 MiB < 256 MiB Infinity Cache). Tiered: n_mats in {3,2,1,0} by
// ws_size; tier 0 == R10 exactly (794 us, proven).
// Pairing layout: dword at (row*1024 + t*64 + lane) packs cols (j, j+1024)
// with j = t*64+lane -- keeps both precompute LDS reads and decode Hs reads
// conflict-free and all global accesses coalesced.

#define BATCH 8
#define NP    2048
#define NPOT  (BATCH * NP)                 // 16384 floats per potential array
#define MAT_ELEMS  ((size_t)BATCH * NP * NP)   // 33,554,432 u16 per matrix
#define MAT_DWORDS (MAT_ELEMS / 2)             // 16,777,216 dwords
#define MAT_BYTES  (MAT_ELEMS * 2)             // 67,108,864 bytes

__device__ __forceinline__ float bcastf(float v) {
  return __int_as_float(__builtin_amdgcn_readfirstlane(__float_as_int(v)));
}

// ---------------------------------------------------------------------------
// Precompute: C as u16 codes a = round(2*acos(|<q,p>|) * 65535/pi).
// m=0: rows=x cols=y (Cxy); m=1: rows=y cols=x (Cyx); m=2: rows=x cols=x (Cxx)
// P0..P3 = acos-poly coeffs * 2 * 65535/pi (scale folded in).
// ---------------------------------------------------------------------------
__global__ __launch_bounds__(512, 8) void precompute_mats(
    const float* __restrict__ x, const float* __restrict__ y,
    unsigned int* __restrict__ mats,
    float P0, float P1, float P2, float P3)
{
  const int bid  = blockIdx.x;          // grid = n_mats * 256
  const int m    = bid >> 8;
  const int b    = (bid >> 5) & 7;
  const int rg   = bid & 31;
  const int tid  = threadIdx.x;
  const int lane = tid & 63;

  __shared__ float4 Pts[NP];

  const float4* rowp; const float4* colp;
  if (m == 0)      { rowp = (const float4*)x; colp = (const float4*)y; }
  else if (m == 1) { rowp = (const float4*)y; colp = (const float4*)x; }
  else             { rowp = (const float4*)x; colp = (const float4*)x; }
  rowp += b * NP; colp += b * NP;

  #pragma unroll
  for (int t = 0; t < 4; ++t)
    Pts[tid + t * 512] = colp[tid + t * 512];
  __syncthreads();

  const int wvu = __builtin_amdgcn_readfirstlane(tid >> 6);
  const int i0  = rg * 64 + wvu * 8;
  float qx[8], qy[8], qz[8], qw[8];
  #pragma unroll
  for (int r = 0; r < 8; ++r) {
    const float4 t4 = rowp[i0 + r];
    qx[r] = bcastf(t4.x); qy[r] = bcastf(t4.y);
    qz[r] = bcastf(t4.z); qw[r] = bcastf(t4.w);
  }

  unsigned int* obase = mats + (size_t)m * MAT_DWORDS
                      + (((size_t)(b * NP + i0)) << 10);

  for (int t = 0; t < 16; ++t) {
    const int j = t * 64 + lane;
    const float4 p0 = Pts[j];
    const float4 p1 = Pts[j + 1024];
    #pragma unroll
    for (int r = 0; r < 8; ++r) {
      float dt0 = fmaf(qx[r], p0.x, fmaf(qy[r], p0.y,
                   fmaf(qz[r], p0.z, qw[r] * p0.w)));
      float dt1 = fmaf(qx[r], p1.x, fmaf(qy[r], p1.y,
                   fmaf(qz[r], p1.z, qw[r] * p1.w)));
      const float u0 = fmaxf(1.0f - fabsf(dt0), 1e-6f);
      const float u1 = fmaxf(1.0f - fabsf(dt1), 1e-6f);
      const float s0 = __builtin_amdgcn_sqrtf(u0);
      const float s1 = __builtin_amdgcn_sqrtf(u1);
      const float g0 = fmaf(fmaf(fmaf(P3, u0, P2), u0, P1), u0, P0);
      const float g1 = fmaf(fmaf(fmaf(P3, u1, P2), u1, P1), u1, P0);
      const unsigned int a0 = (unsigned int)fmaf(s0, g0, 0.5f);  // <= 65533
      const unsigned int a1 = (unsigned int)fmaf(s1, g1, 0.5f);
      obase[(r << 10) + j] = a0 | (a1 << 16);
    }
  }
}

// ---------------------------------------------------------------------------
// Pass kernel: s < n_mats -> u16 decode path; else R10 recompute path.
// ---------------------------------------------------------------------------
__global__ __launch_bounds__(512, 8) void sink_pass_r11(
    const float* __restrict__ x, const float* __restrict__ y,
    const float* __restrict__ wx, const float* __restrict__ wy,
    const unsigned int* __restrict__ mats, int n_mats,
    const float* __restrict__ pot_old, float* __restrict__ pot_new,
    float eps, float c1 /* log2e/eps, 0 on init */,
    float seed_s /* -log2e/eps, 0 on init */,
    float kdec /* (pi/65535)*log2e/eps */,
    float B0, float B1, float B2, float B3 /* acos(u)-poly * 2*log2e/eps */,
    int use_avg)
{
  const int bid  = blockIdx.x;         // grid 1024: s(4) x b(8) x rg(32)
  const int s    = bid >> 8;
  const int b    = (bid >> 5) & 7;
  const int rg   = bid & 31;
  const int tid  = threadIdx.x;
  const int lane = tid & 63;

  __shared__ float4 Pts[NP];   // 32 KB (recompute path only)
  __shared__ float  Hs[NP];    //  8 KB

  const float4* colp; const float* colw; const float* colpot; const float4* rowp;
  if (s == 0)      { colp=(const float4*)y; colw=wy; colpot=pot_old+1*NPOT; rowp=(const float4*)x; }
  else if (s == 1) { colp=(const float4*)x; colw=wx; colpot=pot_old+0*NPOT; rowp=(const float4*)y; }
  else if (s == 2) { colp=(const float4*)x; colw=wx; colpot=pot_old+2*NPOT; rowp=(const float4*)x; }
  else             { colp=(const float4*)y; colw=wy; colpot=pot_old+3*NPOT; rowp=(const float4*)y; }
  colp += b * NP; colw += b * NP; colpot += b * NP;

  const bool use_mat = (s < n_mats);

  if (use_mat) {
    #pragma unroll
    for (int t = 0; t < 4; ++t) {
      const int idx = tid + t * 512;
      Hs[idx] = fmaf(colpot[idx], c1, __builtin_amdgcn_logf(colw[idx]));
    }
  } else {
    #pragma unroll
    for (int t = 0; t < 4; ++t) {
      const int idx = tid + t * 512;
      Pts[idx] = colp[idx];
      Hs[idx] = fmaf(colpot[idx], c1, __builtin_amdgcn_logf(colw[idx]));
    }
  }
  __syncthreads();

  const int wvu = __builtin_amdgcn_readfirstlane(tid >> 6);
  const int i0  = rg * 64 + wvu * 8;
  const int oidx = s * NPOT + b * NP + i0;
  float mh[8];
  #pragma unroll
  for (int r = 0; r < 8; ++r)
    mh[r] = bcastf(pot_old[oidx + r] * seed_s);

  float ss[8] = {0.f, 0.f, 0.f, 0.f, 0.f, 0.f, 0.f, 0.f};

  if (use_mat) {
    // ---------------- u16 decode path ----------------
    const unsigned int* mrow = mats + (size_t)s * MAT_DWORDS
                             + (((size_t)(b * NP + i0)) << 10);
    for (int t = 0; t < 16; ++t) {
      const int j = t * 64 + lane;
      const float h0 = Hs[j];
      const float h1 = Hs[j + 1024];
      #pragma unroll
      for (int r = 0; r < 8; ++r) {
        const unsigned int U = mrow[(r << 10) + j];
        const float a0 = (float)(U & 0xFFFFu);
        const float a1 = (float)(U >> 16);
        ss[r] += __builtin_amdgcn_exp2f(fmaf(a0, -kdec, h0 - mh[r]))
               + __builtin_amdgcn_exp2f(fmaf(a1, -kdec, h1 - mh[r]));
      }
    }
    #pragma unroll
    for (int r = 0; r < 8; ++r) {
      float sv = ss[r];
      #pragma unroll
      for (int off = 32; off >= 1; off >>= 1)
        sv += __shfl_xor(sv, off, 64);
      ss[r] = sv;
    }
    // safety net: two-phase decode re-sweep for out-of-band rows
    #pragma unroll
    for (int r = 0; r < 8; ++r) {
      const bool good = (ss[r] >= 8.6736174e-19f) && (ss[r] <= 1.1529215e18f);
      if (!good) {
        float mv = -3.0e38f;
        for (int t = 0; t < 16; ++t) {
          const int j = t * 64 + lane;
          const unsigned int U = mrow[(r << 10) + j];
          mv = fmaxf(mv, fmaf((float)(U & 0xFFFFu), -kdec, Hs[j]));
          mv = fmaxf(mv, fmaf((float)(U >> 16),     -kdec, Hs[j + 1024]));
        }
        #pragma unroll
        for (int off = 32; off >= 1; off >>= 1)
          mv = fmaxf(mv, __shfl_xor(mv, off, 64));
        mh[r] = mv;
        float sv = 0.0f;
        for (int t = 0; t < 16; ++t) {
          const int j = t * 64 + lane;
          const unsigned int U = mrow[(r << 10) + j];
          sv += __builtin_amdgcn_exp2f(
                  fmaf((float)(U & 0xFFFFu), -kdec, Hs[j] - mh[r]))
              + __builtin_amdgcn_exp2f(
                  fmaf((float)(U >> 16),     -kdec, Hs[j + 1024] - mh[r]));
        }
        #pragma unroll
        for (int off = 32; off >= 1; off >>= 1)
          sv += __shfl_xor(sv, off, 64);
        ss[r] = sv;
      }
    }
  } else {
    // ---------------- R10 recompute path (proven) ----------------
    float qx[8], qy[8], qz[8], qw[8];
    #pragma unroll
    for (int r = 0; r < 8; ++r) {
      const float4 t4 = rowp[b * NP + i0 + r];
      qx[r] = bcastf(t4.x); qy[r] = bcastf(t4.y);
      qz[r] = bcastf(t4.z); qw[r] = bcastf(t4.w);
    }
    for (int t = 0; t < 16; ++t) {
      float4 p[2]; float h[2];
      #pragma unroll
      for (int cc = 0; cc < 2; ++cc) {
        const int j = (t * 2 + cc) * 64 + lane;
        p[cc] = Pts[j];
        h[cc] = Hs[j];
      }
      #pragma unroll
      for (int r = 0; r < 8; ++r) {
        #pragma unroll
        for (int cc = 0; cc < 2; ++cc) {
          const float dt = fmaf(qx[r], p[cc].x,
                            fmaf(qy[r], p[cc].y,
                             fmaf(qz[r], p[cc].z, qw[r] * p[cc].w)));
          const float u  = fmaxf(1.0f - fabsf(dt), 1e-6f);
          const float sq = __builtin_amdgcn_sqrtf(u);
          const float pl = fmaf(fmaf(fmaf(B3, u, B2), u, B1), u, B0);
          const float v  = fmaf(sq, -pl, h[cc]);
          ss[r] += __builtin_amdgcn_exp2f(v - mh[r]);
        }
      }
    }
    #pragma unroll
    for (int r = 0; r < 8; ++r) {
      float sv = ss[r];
      #pragma unroll
      for (int off = 32; off >= 1; off >>= 1)
        sv += __shfl_xor(sv, off, 64);
      ss[r] = sv;
    }
    #pragma unroll
    for (int r = 0; r < 8; ++r) {
      const bool good = (ss[r] >= 8.6736174e-19f) && (ss[r] <= 1.1529215e18f);
      if (!good) {
        float mv = -3.0e38f;
        for (int t = 0; t < 32; ++t) {
          const int j = t * 64 + lane;
          const float4 p = Pts[j];
          const float dt = fmaf(qx[r], p.x,
                            fmaf(qy[r], p.y, fmaf(qz[r], p.z, qw[r] * p.w)));
          const float u  = fmaxf(1.0f - fabsf(dt), 1e-6f);
          const float sq = __builtin_amdgcn_sqrtf(u);
          const float pl = fmaf(fmaf(fmaf(B3, u, B2), u, B1), u, B0);
          mv = fmaxf(mv, fmaf(sq, -pl, Hs[j]));
        }
        #pragma unroll
        for (int off = 32; off >= 1; off >>= 1)
          mv = fmaxf(mv, __shfl_xor(mv, off, 64));
        mh[r] = mv;
        float sv = 0.0f;
        for (int t = 0; t < 32; ++t) {
          const int j = t * 64 + lane;
          const float4 p = Pts[j];
          const float dt = fmaf(qx[r], p.x,
                            fmaf(qy[r], p.y, fmaf(qz[r], p.z, qw[r] * p.w)));
          const float u  = fmaxf(1.0f - fabsf(dt), 1e-6f);
          const float sq = __builtin_amdgcn_sqrtf(u);
          const float pl = fmaf(fmaf(fmaf(B3, u, B2), u, B1), u, B0);
          sv += __builtin_amdgcn_exp2f(fmaf(sq, -pl, Hs[j]) - mh[r]);
        }
        #pragma unroll
        for (int off = 32; off >= 1; off >>= 1)
          sv += __shfl_xor(sv, off, 64);
        ss[r] = sv;
      }
    }
  }

  if (lane == 0) {
    #pragma unroll
    for (int r = 0; r < 8; ++r) {
      float res = -eps * 0.69314718055994531f
                * (mh[r] + __builtin_amdgcn_logf(ss[r]));
      if (use_avg) res = 0.5f * (pot_old[oidx + r] + res);
      pot_new[oidx + r] = res;
    }
  }
}

__global__ __launch_bounds__(256) void loss_kernel(
    const float* __restrict__ pot, const float* __restrict__ wx,
    const float* __restrict__ wy, float* __restrict__ out)
{
  const int tid = threadIdx.x;
  double acc = 0.0;
  for (int idx = tid; idx < NPOT; idx += 256) {
    acc += (double)wx[idx] * ((double)pot[0 * NPOT + idx] - (double)pot[2 * NPOT + idx]);
    acc += (double)wy[idx] * ((double)pot[1 * NPOT + idx] - (double)pot[3 * NPOT + idx]);
  }
  #pragma unroll
  for (int off = 32; off >= 1; off >>= 1)
    acc += __shfl_xor(acc, off, 64);
  __shared__ double wsum[4];
  if ((tid & 63) == 0) wsum[tid >> 6] = acc;
  __syncthreads();
  if (tid == 0)
    out[0] = (float)((wsum[0] + wsum[1] + wsum[2] + wsum[3]) / (double)BATCH);
}

extern "C" void kernel_launch(void* const* d_in, const int* in_sizes, int n_in,
                              void* d_out, int out_size, void* d_ws, size_t ws_size,
                              hipStream_t stream)
{
  const float* x  = (const float*)d_in[0];
  const float* y  = (const float*)d_in[1];
  const float* wx = (const float*)d_in[2];
  const float* wy = (const float*)d_in[3];

  const size_t potBytes = (size_t)2 * 4 * NPOT * 4;   // 524,288
  int n_mats = 0;
  if      (ws_size >= 3 * MAT_BYTES + potBytes) n_mats = 3;
  else if (ws_size >= 2 * MAT_BYTES + potBytes) n_mats = 2;
  else if (ws_size >= 1 * MAT_BYTES + potBytes) n_mats = 1;

  unsigned int* mats = (unsigned int*)d_ws;
  float* pot[2];
  pot[0] = (float*)((char*)d_ws + (size_t)n_mats * MAT_BYTES);
  pot[1] = pot[0] + 4 * NPOT;

  // geomloss epsilon_schedule(p=2, diameter=3.15, blur=0.01, scaling=0.5)
  double eps_list[16]; int ne = 0;
  eps_list[ne++] = 3.15 * 3.15;
  const double stop = 2.0 * log(0.01), step = 2.0 * log(0.5);
  for (double e = 2.0 * log(3.15); e > stop; e += step) eps_list[ne++] = exp(e);
  eps_list[ne++] = 0.01 * 0.01;   // ne == 11

  const double LOG2E = 1.4426950408889634;
  const double PI    = 3.14159265358979323846;
  // acos(d) ~= sqrt(u)*(b0 + b1 u + b2 u^2 + b3 u^3), u = 1-d, |err|<=6.7e-5
  const double b0 = 1.4141461, b1 = 0.1197803, b2 = 0.0180731, b3 = 0.0187293;
  const dim3 grid(1024), blkPass(512), blkLoss(256);
  int cur = 0;

  if (n_mats > 0) {
    const double S2 = 2.0 * 65535.0 / PI;   // fold 2*65535/pi into coeffs
    hipLaunchKernelGGL(precompute_mats, dim3(n_mats * 256), blkPass, 0, stream,
        x, y, mats,
        (float)(b0 * S2), (float)(b1 * S2), (float)(b2 * S2), (float)(b3 * S2));
  }

  auto launch_pass = [&](double e, float c1f, float seedf, int avg) {
    const double sc = 2.0 * LOG2E / e;
    const double kd = (PI / 65535.0) * (LOG2E / e);
    hipLaunchKernelGGL(sink_pass_r11, grid, blkPass, 0, stream,
        x, y, wx, wy, mats, n_mats, pot[cur], pot[1 - cur],
        (float)e, c1f, seedf, (float)kd,
        (float)(b0 * sc), (float)(b1 * sc), (float)(b2 * sc), (float)(b3 * sc), avg);
    cur ^= 1;
  };

  // init pass: no potential in h, m_hat = 0, replace-mode
  launch_pass(eps_list[0], 0.0f, 0.0f, 0);
  // annealing loop, averaging update
  for (int k = 0; k < ne; ++k) {
    const double e = eps_list[k];
    launch_pass(e, (float)(LOG2E / e), (float)(-LOG2E / e), 1);
  }
  // final extrapolation, replace-mode
  {
    const double e = eps_list[ne - 1];
    launch_pass(e, (float)(LOG2E / e), (float)(-LOG2E / e), 0);
  }

  hipLaunchKernelGGL(loss_kernel, dim3(1), blkLoss, 0, stream,
      pot[cur], wx, wy, (float*)d_out);
}